// Round 8
// baseline (206.971 us; speedup 1.0000x reference)
//
#include <hip/hip_runtime.h>
#include <hip/hip_bf16.h>

// Problem constants (N=2, C=256, H=W=64) — float32 I/O per reference.
#define NBATCH 2
#define CCH    256
#define LLEN   4096      // H*W
#define NGROUP 8
#define CPG    32        // C / NGROUP
#define NHEAD  4
#define HD     64        // C / NHEAD
#define GEPS   1e-5f
#define QTILE  128       // attn q rows per block (32 per wave)
#define KTILE  64        // attn keys per iteration
#define KSPLIT 4
#define KEYS_PER_PART (LLEN / KSPLIT)    // 1024
#define AITERS (KEYS_PER_PART / KTILE)   // 16
// q pre-scale: hd^-0.5 * log2(e); scores then feed v_exp_f32 (2^x) directly.
#define QSCALE 0.18033688011112042f

typedef short bf16x8 __attribute__((ext_vector_type(8)));
typedef float f32x4  __attribute__((ext_vector_type(4)));

// fp32 -> bf16 bits, round-to-nearest-even (scalar path)
__device__ __forceinline__ unsigned short f2b(float f) {
  unsigned u = __float_as_uint(f);
  u += 0x7FFFu + ((u >> 16) & 1u);
  return (unsigned short)(u >> 16);
}
// HW packed cvt (v_cvt_pk_bf16_f32); a -> low 16, b -> high 16
__device__ __forceinline__ unsigned pack2bf(float a, float b) {
  __hip_bfloat162 h = __float22bfloat162_rn(make_float2(a, b));
  union { __hip_bfloat162 h; unsigned u; } c;
  c.h = h;
  return c.u;
}
__device__ __forceinline__ float b2f(unsigned short h) {
  return __uint_as_float(((unsigned int)h) << 16);
}
__device__ __forceinline__ float exp2_(float x) {
#if __has_builtin(__builtin_amdgcn_exp2f)
  return __builtin_amdgcn_exp2f(x);
#else
  return exp2f(x);
#endif
}
// bf16x8 fragment load from LDS as two b64 reads (8B-aligned rows are legal;
// odd-word row strides give conflict-free bank spread)
__device__ __forceinline__ bf16x8 ldsa8(const unsigned short* p) {
  union { bf16x8 v; uint2 d[2]; } u;
  u.d[0] = *(const uint2*)(p);
  u.d[1] = *(const uint2*)(p + 4);
  return u.v;
}

// ------- setup: wcvt (blocks 0..255) | gn partial sums (256..383) | mask (384..415) -------
__global__ __launch_bounds__(256) void setup_kernel(
    const float* __restrict__ qw, const float* __restrict__ kw,
    const float* __restrict__ vw, const float* __restrict__ pw,
    const float* __restrict__ qb, const float* __restrict__ kb,
    const float* __restrict__ vb, const float* __restrict__ pb,
    const float* __restrict__ x, const int* __restrict__ mask,
    unsigned short* __restrict__ w16, float* __restrict__ bias_ws,
    float* __restrict__ part, float* __restrict__ out2) {
  __shared__ float rs[4], rss[4];
  const int b = blockIdx.x;
  const int t = threadIdx.x;
  if (b < 256) {
    const int idx = b * 256 + t;               // float4 units; 65536 total
    const int m = idx >> 14;
    const float* src[4] = {qw, kw, vw, pw};
    const float sc = (m == 0) ? QSCALE : 1.0f;
    const float4 v = ((const float4*)src[m])[idx & 16383];
    ushort4 o;
    o.x = f2b(v.x * sc); o.y = f2b(v.y * sc);
    o.z = f2b(v.z * sc); o.w = f2b(v.w * sc);
    ((ushort4*)w16)[idx] = o;
    if (b == 0) {
      bias_ws[t]       = qb[t] * QSCALE;
      bias_ws[256 + t] = kb[t];
      bias_ws[512 + t] = vb[t];
      bias_ws[768 + t] = pb[t];
    }
  } else if (b < 384) {
    const int sb = b - 256;                    // 128 = 16 groups x 8 sub
    const int gidx = sb >> 3, sub = sb & 7;
    const float4* xp = (const float4*)(x + (size_t)gidx * (CPG * LLEN)) + (size_t)sub * 4096;
    float s = 0.f, ss = 0.f;
    for (int i = t; i < 4096; i += 256) {
      const float4 v = xp[i];
      s += v.x + v.y + v.z + v.w;
      ss = fmaf(v.x, v.x, ss);
      ss = fmaf(v.y, v.y, ss);
      ss = fmaf(v.z, v.z, ss);
      ss = fmaf(v.w, v.w, ss);
    }
#pragma unroll
    for (int off = 32; off; off >>= 1) {
      s  += __shfl_down(s, off);
      ss += __shfl_down(ss, off);
    }
    if ((t & 63) == 0) { rs[t >> 6] = s; rss[t >> 6] = ss; }
    __syncthreads();
    if (t == 0) {
      part[sb * 2 + 0] = rs[0] + rs[1] + rs[2] + rs[3];
      part[sb * 2 + 1] = rss[0] + rss[1] + rss[2] + rss[3];
    }
  } else {
    const int i = (b - 384) * 256 + t;
    out2[i] = (float)mask[i];
  }
}

// ------- GroupNorm apply (stats reduced inline from part) + transpose -> bf16 [n,l,c] -------
__global__ __launch_bounds__(256) void gn_apply_kernel(const float* __restrict__ x,
                                                       const float* __restrict__ w,
                                                       const float* __restrict__ b,
                                                       const float* __restrict__ part,
                                                       unsigned short* __restrict__ xn16) {
  const int l0 = blockIdx.x * 32, c0 = blockIdx.y * 32, n = blockIdx.z;
  const int g16 = n * 8 + (c0 >> 5);
  float s = 0.f, ss = 0.f;
#pragma unroll
  for (int i = 0; i < 8; i++) {
    s  += part[(g16 * 8 + i) * 2 + 0];
    ss += part[(g16 * 8 + i) * 2 + 1];
  }
  const float inv_cnt = 1.0f / (float)(CPG * LLEN);
  const float mu = s * inv_cnt;
  const float rsg = rsqrtf(ss * inv_cnt - mu * mu + GEPS);
  __shared__ float tile[32][33];
  const int tx = threadIdx.x & 31, ty = threadIdx.x >> 5;
#pragma unroll
  for (int i = 0; i < 4; i++) {
    const int c = c0 + ty + 8 * i;
    const float wc = w[c], bc = b[c];
    const float v = x[((size_t)n * CCH + c) * LLEN + l0 + tx];
    tile[ty + 8 * i][tx] = (v - mu) * rsg * wc + bc;
  }
  __syncthreads();
#pragma unroll
  for (int i = 0; i < 4; i++) {
    const int l = l0 + ty + 8 * i;
    xn16[((size_t)n * LLEN + l) * CCH + c0 + tx] = f2b(tile[tx][ty + 8 * i]);
  }
}

// ------- QKV GEMM, bf16 MFMA; A rows staged through LDS (coalesced) -------
__global__ __launch_bounds__(256) void qkv_mfma_kernel(
    const unsigned short* __restrict__ xn16,
    const unsigned short* __restrict__ w16,    // [3][256][256]
    const float* __restrict__ bias_ws,         // [3][256]
    unsigned short* __restrict__ q16,
    unsigned short* __restrict__ k16,
    unsigned short* __restrict__ v16) {
  __shared__ __align__(16) unsigned short xS[32][260];
  __shared__ __align__(16) unsigned short wT[256][36];
  const int t = threadIdx.x;
  const int lane = t & 63, wv = t >> 6;
  const int col = lane & 15, quad = lane >> 4;
  const int m0 = blockIdx.x * 32;            // flat (n*L + l) row base
  const int wsel = blockIdx.y;
  const unsigned short* wsrc = w16 + (size_t)wsel * (CCH * CCH);
  const int cw = wv * 64;

  // stage xn rows m0..m0+31: thread t loads row t>>3, 64B chunk t&7 (coalesced)
  {
    const int r = t >> 3, c = (t & 7) * 32;
    const unsigned short* src = xn16 + (size_t)(m0 + r) * CCH + c;
    const uint4 a0 = *(const uint4*)(src);
    const uint4 a1 = *(const uint4*)(src + 8);
    const uint4 a2 = *(const uint4*)(src + 16);
    const uint4 a3 = *(const uint4*)(src + 24);
    uint2* d = (uint2*)&xS[r][c];
    d[0] = make_uint2(a0.x, a0.y); d[1] = make_uint2(a0.z, a0.w);
    d[2] = make_uint2(a1.x, a1.y); d[3] = make_uint2(a1.z, a1.w);
    d[4] = make_uint2(a2.x, a2.y); d[5] = make_uint2(a2.z, a2.w);
    d[6] = make_uint2(a3.x, a3.y); d[7] = make_uint2(a3.z, a3.w);
  }
  __syncthreads();
  bf16x8 ax[2][8];
#pragma unroll
  for (int mt = 0; mt < 2; mt++)
#pragma unroll
    for (int kc = 0; kc < 8; kc++)
      ax[mt][kc] = ldsa8(&xS[mt * 16 + col][kc * 32 + quad * 8]);

  f32x4 acc[2][4];
#pragma unroll
  for (int mt = 0; mt < 2; mt++)
#pragma unroll
    for (int ct = 0; ct < 4; ct++) acc[mt][ct] = {0.f, 0.f, 0.f, 0.f};

  const int scout = t >> 2;          // 0..63
  const int sj = (t & 3) * 8;
  for (int kc = 0; kc < 8; kc++) {
    __syncthreads();
#pragma unroll
    for (int i = 0; i < 4; i++) {
      const int cc = scout + i * 64;
      const uint4 wv4 = *(const uint4*)(wsrc + (size_t)cc * CCH + kc * 32 + sj);
      uint2* d = (uint2*)&wT[cc][sj];
      d[0] = make_uint2(wv4.x, wv4.y);
      d[1] = make_uint2(wv4.z, wv4.w);
    }
    __syncthreads();
    if (wsel < 2) {
#pragma unroll
      for (int ct = 0; ct < 4; ct++) {
        const bf16x8 bw = ldsa8(&wT[cw + ct * 16 + col][quad * 8]);
#pragma unroll
        for (int mt = 0; mt < 2; mt++)
          acc[mt][ct] = __builtin_amdgcn_mfma_f32_16x16x32_bf16(ax[mt][kc], bw, acc[mt][ct], 0, 0, 0);
      }
    } else {
#pragma unroll
      for (int ct = 0; ct < 4; ct++) {
        const bf16x8 bw = ldsa8(&wT[cw + ct * 16 + col][quad * 8]);
#pragma unroll
        for (int mt = 0; mt < 2; mt++)
          acc[mt][ct] = __builtin_amdgcn_mfma_f32_16x16x32_bf16(bw, ax[mt][kc], acc[mt][ct], 0, 0, 0);
      }
    }
  }
  const float* bp = bias_ws + wsel * CCH;
  if (wsel < 2) {
    unsigned short* dst = (wsel == 0) ? q16 : k16;
#pragma unroll
    for (int ct = 0; ct < 4; ct++) {
      const float bias = bp[cw + ct * 16 + col];
#pragma unroll
      for (int mt = 0; mt < 2; mt++)
#pragma unroll
        for (int r = 0; r < 4; r++)
          dst[(size_t)(m0 + mt * 16 + quad * 4 + r) * CCH + cw + ct * 16 + col] =
              f2b(acc[mt][ct][r] + bias);
    }
  } else {
    const int n = m0 >> 12, l0 = m0 & 4095;
#pragma unroll
    for (int ct = 0; ct < 4; ct++)
#pragma unroll
      for (int r = 0; r < 4; r++) {
        const int cout = cw + ct * 16 + quad * 4 + r;
        const float bias = bp[cout];
#pragma unroll
        for (int mt = 0; mt < 2; mt++)
          v16[((size_t)(n * CCH + cout)) * LLEN + l0 + mt * 16 + col] =
              f2b(acc[mt][ct][r] + bias);
      }
  }
}

// ------- Flash attention: LDS-staged K/V, 2^s softmax, MFMA denominators.
//         LDS stride 68 ushorts (word-stride ≡ 2 mod 32) + b64 accesses:
//         uniform 4-lanes-per-bank-pair -> conflict-free. -------
__global__ __launch_bounds__(256, 4) void attn_mfma_kernel(
    const unsigned short* __restrict__ q16,   // [n,l,c], pre-scaled (QSCALE folded)
    const unsigned short* __restrict__ k16,   // [n,l,c]
    const unsigned short* __restrict__ v16,   // [n,c,l]
    unsigned short* __restrict__ opA,         // bf16 parts 0,1 (each [n,l,c])
    unsigned short* __restrict__ opB,         // bf16 parts 2,3
    float* __restrict__ lpart) {              // [part][n][h][l]
  __shared__ __align__(16) unsigned short kT[64][68];     // [key][ch]
  __shared__ __align__(16) unsigned short vT[64][68];     // [ch][key]
  __shared__ __align__(16) unsigned short pT[4][32][68];  // per-wave [qrow][key]
  const int t = threadIdx.x;
  const int lane = t & 63, wv = t >> 6;
  const int col = lane & 15, quad = lane >> 4;
  const int q0 = blockIdx.x * QTILE;
  const int n = blockIdx.y >> 2, h = blockIdx.y & 3;
  const int part = blockIdx.z;
  const int hc = h * HD;
  const size_t baseNL = (size_t)n * LLEN;
  const int m_base = q0 + wv * 32;

  bf16x8 bq[2][2];
#pragma unroll
  for (int mt = 0; mt < 2; mt++) {
    const unsigned short* qr = q16 + (baseNL + m_base + mt * 16 + col) * CCH + hc + quad * 8;
    bq[mt][0] = *(const bf16x8*)qr;
    bq[mt][1] = *(const bf16x8*)(qr + 32);
  }
  bf16x8 bones;
#pragma unroll
  for (int i = 0; i < 8; i++) bones[i] = (short)0x3F80;   // bf16 1.0

  f32x4 o[2][4], lacc[2];
#pragma unroll
  for (int mt = 0; mt < 2; mt++) {
    lacc[mt] = {0.f, 0.f, 0.f, 0.f};
#pragma unroll
    for (int ct = 0; ct < 4; ct++) o[mt][ct] = {0.f, 0.f, 0.f, 0.f};
  }

  const int srow = t >> 3;
  const int scol = (t & 7) * 8;
  const unsigned short* kgp = k16 + (baseNL + srow) * CCH + hc + scol;
  const unsigned short* vgp = v16 + ((size_t)(n * CCH + hc + srow)) * LLEN + scol;
  const size_t krstep = (size_t)32 * CCH;
  const size_t vrstep = (size_t)32 * LLEN;

  int kt = part * KEYS_PER_PART;
  uint4 rk0 = *(const uint4*)(kgp + (size_t)kt * CCH);
  uint4 rk1 = *(const uint4*)(kgp + (size_t)kt * CCH + krstep);
  uint4 rv0 = *(const uint4*)(vgp + kt);
  uint4 rv1 = *(const uint4*)(vgp + kt + vrstep);

  for (int it = 0; it < AITERS; it++) {
    __syncthreads();
    {
      uint2* d;
      d = (uint2*)&kT[srow][scol];      d[0] = make_uint2(rk0.x, rk0.y); d[1] = make_uint2(rk0.z, rk0.w);
      d = (uint2*)&kT[srow + 32][scol]; d[0] = make_uint2(rk1.x, rk1.y); d[1] = make_uint2(rk1.z, rk1.w);
      d = (uint2*)&vT[srow][scol];      d[0] = make_uint2(rv0.x, rv0.y); d[1] = make_uint2(rv0.z, rv0.w);
      d = (uint2*)&vT[srow + 32][scol]; d[0] = make_uint2(rv1.x, rv1.y); d[1] = make_uint2(rv1.z, rv1.w);
    }
    const int ktn = (it + 1 < AITERS) ? kt + KTILE : kt;
    rk0 = *(const uint4*)(kgp + (size_t)ktn * CCH);
    rk1 = *(const uint4*)(kgp + (size_t)ktn * CCH + krstep);
    rv0 = *(const uint4*)(vgp + ktn);
    rv1 = *(const uint4*)(vgp + ktn + vrstep);
    __syncthreads();

#pragma unroll
    for (int nt = 0; nt < 4; nt++) {
      const bf16x8 a0 = ldsa8(&kT[nt * 16 + col][quad * 8]);
      const bf16x8 a1 = ldsa8(&kT[nt * 16 + col][32 + quad * 8]);
#pragma unroll
      for (int mt = 0; mt < 2; mt++) {
        f32x4 s = {0.f, 0.f, 0.f, 0.f};
        s = __builtin_amdgcn_mfma_f32_16x16x32_bf16(a0, bq[mt][0], s, 0, 0, 0);
        s = __builtin_amdgcn_mfma_f32_16x16x32_bf16(a1, bq[mt][1], s, 0, 0, 0);
        const float p0 = exp2_(s[0]);
        const float p1 = exp2_(s[1]);
        const float p2 = exp2_(s[2]);
        const float p3 = exp2_(s[3]);
        uint2 w;
        w.x = pack2bf(p0, p1);
        w.y = pack2bf(p2, p3);
        *(uint2*)&pT[wv][mt * 16 + col][nt * 16 + quad * 4] = w;
      }
    }
    bf16x8 pa[2][2];
#pragma unroll
    for (int mt = 0; mt < 2; mt++) {
      pa[mt][0] = ldsa8(&pT[wv][mt * 16 + col][quad * 8]);
      pa[mt][1] = ldsa8(&pT[wv][mt * 16 + col][32 + quad * 8]);
      lacc[mt] = __builtin_amdgcn_mfma_f32_16x16x32_bf16(pa[mt][0], bones, lacc[mt], 0, 0, 0);
      lacc[mt] = __builtin_amdgcn_mfma_f32_16x16x32_bf16(pa[mt][1], bones, lacc[mt], 0, 0, 0);
    }
#pragma unroll
    for (int ct = 0; ct < 4; ct++) {
      const bf16x8 b0 = ldsa8(&vT[ct * 16 + col][quad * 8]);
      const bf16x8 b1 = ldsa8(&vT[ct * 16 + col][32 + quad * 8]);
#pragma unroll
      for (int mt = 0; mt < 2; mt++) {
        o[mt][ct] = __builtin_amdgcn_mfma_f32_16x16x32_bf16(pa[mt][0], b0, o[mt][ct], 0, 0, 0);
        o[mt][ct] = __builtin_amdgcn_mfma_f32_16x16x32_bf16(pa[mt][1], b1, o[mt][ct], 0, 0, 0);
      }
    }
    kt = ktn;
  }

  if (col == 0) {
#pragma unroll
    for (int mt = 0; mt < 2; mt++)
#pragma unroll
      for (int r = 0; r < 4; r++)
        lpart[((size_t)(part * NBATCH + n) * NHEAD + h) * LLEN +
              m_base + mt * 16 + quad * 4 + r] = lacc[mt][r];
  }
  const size_t TS = (size_t)NBATCH * LLEN * CCH;
  unsigned short* op = (part < 2) ? (opA + (size_t)part * TS) : (opB + (size_t)(part - 2) * TS);
#pragma unroll
  for (int mt = 0; mt < 2; mt++)
#pragma unroll
    for (int r = 0; r < 4; r++) {
      const size_t rowoff = (baseNL + m_base + mt * 16 + quad * 4 + r) * CCH + hc;
#pragma unroll
      for (int ct = 0; ct < 4; ct++)
        op[rowoff + ct * 16 + col] = f2b(o[mt][ct][r]);
    }
}

// ------- Proj GEMM: split-K combine + normalize staged through LDS (coalesced),
//         bf16 MFMA, + bias + residual -> fp32 out [n,c,l] -------
__global__ __launch_bounds__(256) void proj_mfma_kernel(
    const unsigned short* __restrict__ opA,     // bf16 parts 0,1
    const unsigned short* __restrict__ opB,     // bf16 parts 2,3
    const float* __restrict__ lpart,            // [part][n][h][l]
    const unsigned short* __restrict__ pw16,    // [256][256] bf16
    const float* __restrict__ pbias,            // [256]
    const float* __restrict__ x,
    float* __restrict__ out) {
  __shared__ __align__(16) unsigned short aS[16][260];
  __shared__ __align__(16) unsigned short wT[256][36];
  const size_t TS = (size_t)NBATCH * LLEN * CCH;
  const size_t LPS = (size_t)NBATCH * NHEAD * LLEN;
  const int t = threadIdx.x;
  const int lane = t & 63, wv = t >> 6;
  const int col = lane & 15, quad = lane >> 4;
  const int m0 = blockIdx.x * 16;
  const int cw = wv * 64;
  const int n = m0 >> 12, l0 = m0 & 4095;

  // stage summed+normalized partials: thread t -> row t>>4, 16B chunks (t&15), (t&15)+16
  {
    const int row = t >> 4;
    const int l = l0 + row;
    const int h0 = (t & 15) >> 3;
    float ls0 = 0.f, ls1 = 0.f;
#pragma unroll
    for (int p = 0; p < 4; p++) {
      ls0 += lpart[p * LPS + ((size_t)n * NHEAD + h0) * LLEN + l];
      ls1 += lpart[p * LPS + ((size_t)n * NHEAD + h0 + 2) * LLEN + l];
    }
    const float linv0 = 1.0f / ls0;
    const float linv1 = 1.0f / ls1;
#pragma unroll
    for (int half = 0; half < 2; half++) {
      const int c = (t & 15) + half * 16;
      const size_t e = (size_t)(m0 + row) * CCH + c * 8;
      const uint4 u0 = *(const uint4*)(opA + e);
      const uint4 u1 = *(const uint4*)(opA + TS + e);
      const uint4 u2 = *(const uint4*)(opB + e);
      const uint4 u3 = *(const uint4*)(opB + TS + e);
      const float f = half ? linv1 : linv0;
      unsigned r[4];
#pragma unroll
      for (int i = 0; i < 4; i++) {
        const unsigned a = (&u0.x)[i], bb = (&u1.x)[i], cc = (&u2.x)[i], dd = (&u3.x)[i];
        const float lo = (b2f((unsigned short)a) + b2f((unsigned short)bb) +
                          b2f((unsigned short)cc) + b2f((unsigned short)dd)) * f;
        const float hi = (b2f((unsigned short)(a >> 16)) + b2f((unsigned short)(bb >> 16)) +
                          b2f((unsigned short)(cc >> 16)) + b2f((unsigned short)(dd >> 16))) * f;
        r[i] = pack2bf(lo, hi);
      }
      uint2* d = (uint2*)&aS[row][c * 8];
      d[0] = make_uint2(r[0], r[1]);
      d[1] = make_uint2(r[2], r[3]);
    }
  }
  __syncthreads();
  bf16x8 ba[8];
#pragma unroll
  for (int kc = 0; kc < 8; kc++)
    ba[kc] = ldsa8(&aS[col][kc * 32 + quad * 8]);

  f32x4 acc[4];
#pragma unroll
  for (int ct = 0; ct < 4; ct++) acc[ct] = {0.f, 0.f, 0.f, 0.f};

  const int scout = t >> 2;
  const int sj = (t & 3) * 8;
  for (int kc = 0; kc < 8; kc++) {
    __syncthreads();
#pragma unroll
    for (int i = 0; i < 4; i++) {
      const int cc = scout + i * 64;
      const uint4 wv4 = *(const uint4*)(pw16 + (size_t)cc * CCH + kc * 32 + sj);
      uint2* d = (uint2*)&wT[cc][sj];
      d[0] = make_uint2(wv4.x, wv4.y);
      d[1] = make_uint2(wv4.z, wv4.w);
    }
    __syncthreads();
#pragma unroll
    for (int ct = 0; ct < 4; ct++) {
      const bf16x8 aw = ldsa8(&wT[cw + ct * 16 + col][quad * 8]);
      acc[ct] = __builtin_amdgcn_mfma_f32_16x16x32_bf16(aw, ba[kc], acc[ct], 0, 0, 0);
    }
  }
  const int l = l0 + col;
#pragma unroll
  for (int ct = 0; ct < 4; ct++)
#pragma unroll
    for (int r = 0; r < 4; r++) {
      const int cout = cw + ct * 16 + quad * 4 + r;
      const size_t idx = ((size_t)(n * CCH + cout)) * LLEN + l;
      out[idx] = acc[ct][r] + pbias[cout] + x[idx];
    }
}

extern "C" void kernel_launch(void* const* d_in, const int* in_sizes, int n_in,
                              void* d_out, int out_size, void* d_ws, size_t ws_size,
                              hipStream_t stream) {
  (void)in_sizes; (void)n_in; (void)out_size; (void)ws_size;
  const float* x      = (const float*)d_in[0];
  const int*   mask   = (const int*)d_in[1];
  const float* norm_w = (const float*)d_in[2];
  const float* norm_b = (const float*)d_in[3];
  const float* q_w    = (const float*)d_in[4];
  const float* q_b    = (const float*)d_in[5];
  const float* k_w    = (const float*)d_in[6];
  const float* k_b    = (const float*)d_in[7];
  const float* v_w    = (const float*)d_in[8];
  const float* v_b    = (const float*)d_in[9];
  const float* p_w    = (const float*)d_in[10];
  const float* p_b    = (const float*)d_in[11];

  const size_t TSZ = (size_t)NBATCH * LLEN * CCH;   // 2097152 elements
  unsigned short* xn16 = (unsigned short*)d_ws;     // TSZ
  unsigned short* q16  = xn16 + TSZ;
  unsigned short* k16  = q16 + TSZ;
  unsigned short* v16  = k16 + TSZ;
  unsigned short* opA  = v16 + TSZ;                 // 2*TSZ
  unsigned short* opB  = opA + 2 * TSZ;             // 2*TSZ
  unsigned short* w16  = opB + 2 * TSZ;             // 4*65536
  float* bias_ws = (float*)(w16 + 4 * 65536);       // 4*256
  float* lpart   = bias_ws + 1024;                  // KSPLIT*N*H*L
  float* part    = lpart + (size_t)KSPLIT * NBATCH * NHEAD * LLEN;  // 256
  // total ~33 MB

  float* out  = (float*)d_out;
  float* out2 = out + TSZ;   // mask chunk

  setup_kernel<<<416, 256, 0, stream>>>(q_w, k_w, v_w, p_w, q_b, k_b, v_b, p_b,
                                        x, mask, w16, bias_ws, part, out2);
  gn_apply_kernel<<<dim3(LLEN / 32, CCH / 32, NBATCH), 256, 0, stream>>>(
      x, norm_w, norm_b, part, xn16);
  qkv_mfma_kernel<<<dim3((NBATCH * LLEN) / 32, 3), 256, 0, stream>>>(
      xn16, w16, bias_ws, q16, k16, v16);
  attn_mfma_kernel<<<dim3(LLEN / QTILE, NBATCH * NHEAD, KSPLIT), 256, 0, stream>>>(
      q16, k16, v16, opA, opB, lpart);
  proj_mfma_kernel<<<(NBATCH * LLEN) / 16, 256, 0, stream>>>(
      opA, opB, lpart, w16 + 3 * 65536, bias_ws + 768, x, out);
}

// Round 9
// 167.441 us; speedup vs baseline: 1.2361x; 1.2361x over previous
//
#include <hip/hip_runtime.h>
#include <hip/hip_bf16.h>

// Problem constants (N=2, C=256, H=W=64) — float32 I/O per reference.
#define NBATCH 2
#define CCH    256
#define LLEN   4096      // H*W
#define NGROUP 8
#define CPG    32        // C / NGROUP
#define NHEAD  4
#define HD     64        // C / NHEAD
#define GEPS   1e-5f
#define QTILE  128       // attn q rows per block (32 per wave)
#define KTILE  64        // attn keys per iteration
#define KSPLIT 4
#define KEYS_PER_PART (LLEN / KSPLIT)    // 1024
#define AITERS (KEYS_PER_PART / KTILE)   // 16
// q pre-scale: hd^-0.5 * log2(e); scores then feed v_exp_f32 (2^x) directly.
#define QSCALE 0.18033688011112042f
#define RS 264           // GEMM LDS row stride (ushorts): 132 words ≡ 4 mod 32 -> balanced b128

typedef short bf16x8 __attribute__((ext_vector_type(8)));
typedef float f32x4  __attribute__((ext_vector_type(4)));

// fp32 -> bf16 bits, round-to-nearest-even (scalar path)
__device__ __forceinline__ unsigned short f2b(float f) {
  unsigned u = __float_as_uint(f);
  u += 0x7FFFu + ((u >> 16) & 1u);
  return (unsigned short)(u >> 16);
}
// HW packed cvt (v_cvt_pk_bf16_f32); a -> low 16, b -> high 16
__device__ __forceinline__ unsigned pack2bf(float a, float b) {
  __hip_bfloat162 h = __float22bfloat162_rn(make_float2(a, b));
  union { __hip_bfloat162 h; unsigned u; } c;
  c.h = h;
  return c.u;
}
__device__ __forceinline__ float b2f(unsigned short h) {
  return __uint_as_float(((unsigned int)h) << 16);
}
__device__ __forceinline__ float exp2_(float x) {
#if __has_builtin(__builtin_amdgcn_exp2f)
  return __builtin_amdgcn_exp2f(x);
#else
  return exp2f(x);
#endif
}

// ------- setup: wcvt (blocks 0..255) | gn partial sums (256..383) | mask (384..415) -------
__global__ __launch_bounds__(256) void setup_kernel(
    const float* __restrict__ qw, const float* __restrict__ kw,
    const float* __restrict__ vw, const float* __restrict__ pw,
    const float* __restrict__ qb, const float* __restrict__ kb,
    const float* __restrict__ vb, const float* __restrict__ pb,
    const float* __restrict__ x, const int* __restrict__ mask,
    unsigned short* __restrict__ w16, float* __restrict__ bias_ws,
    float* __restrict__ part, float* __restrict__ out2) {
  __shared__ float rs[4], rss[4];
  const int b = blockIdx.x;
  const int t = threadIdx.x;
  if (b < 256) {
    const int idx = b * 256 + t;               // float4 units; 65536 total
    const int m = idx >> 14;
    const float* src[4] = {qw, kw, vw, pw};
    const float sc = (m == 0) ? QSCALE : 1.0f;
    const float4 v = ((const float4*)src[m])[idx & 16383];
    ushort4 o;
    o.x = f2b(v.x * sc); o.y = f2b(v.y * sc);
    o.z = f2b(v.z * sc); o.w = f2b(v.w * sc);
    ((ushort4*)w16)[idx] = o;
    if (b == 0) {
      bias_ws[t]       = qb[t] * QSCALE;
      bias_ws[256 + t] = kb[t];
      bias_ws[512 + t] = vb[t];
      bias_ws[768 + t] = pb[t];
    }
  } else if (b < 384) {
    const int sb = b - 256;                    // 128 = 16 groups x 8 sub
    const int gidx = sb >> 3, sub = sb & 7;
    const float4* xp = (const float4*)(x + (size_t)gidx * (CPG * LLEN)) + (size_t)sub * 4096;
    float s = 0.f, ss = 0.f;
    for (int i = t; i < 4096; i += 256) {
      const float4 v = xp[i];
      s += v.x + v.y + v.z + v.w;
      ss = fmaf(v.x, v.x, ss);
      ss = fmaf(v.y, v.y, ss);
      ss = fmaf(v.z, v.z, ss);
      ss = fmaf(v.w, v.w, ss);
    }
#pragma unroll
    for (int off = 32; off; off >>= 1) {
      s  += __shfl_down(s, off);
      ss += __shfl_down(ss, off);
    }
    if ((t & 63) == 0) { rs[t >> 6] = s; rss[t >> 6] = ss; }
    __syncthreads();
    if (t == 0) {
      part[sb * 2 + 0] = rs[0] + rs[1] + rs[2] + rs[3];
      part[sb * 2 + 1] = rss[0] + rss[1] + rss[2] + rss[3];
    }
  } else {
    const int i = (b - 384) * 256 + t;
    out2[i] = (float)mask[i];
  }
}

// ------- GroupNorm apply (stats reduced inline from part) + transpose -> bf16 [n,l,c] -------
__global__ __launch_bounds__(256) void gn_apply_kernel(const float* __restrict__ x,
                                                       const float* __restrict__ w,
                                                       const float* __restrict__ b,
                                                       const float* __restrict__ part,
                                                       unsigned short* __restrict__ xn16) {
  const int l0 = blockIdx.x * 32, c0 = blockIdx.y * 32, n = blockIdx.z;
  const int g16 = n * 8 + (c0 >> 5);
  float s = 0.f, ss = 0.f;
#pragma unroll
  for (int i = 0; i < 8; i++) {
    s  += part[(g16 * 8 + i) * 2 + 0];
    ss += part[(g16 * 8 + i) * 2 + 1];
  }
  const float inv_cnt = 1.0f / (float)(CPG * LLEN);
  const float mu = s * inv_cnt;
  const float rsg = rsqrtf(ss * inv_cnt - mu * mu + GEPS);
  __shared__ float tile[32][33];
  const int tx = threadIdx.x & 31, ty = threadIdx.x >> 5;
#pragma unroll
  for (int i = 0; i < 4; i++) {
    const int c = c0 + ty + 8 * i;
    const float wc = w[c], bc = b[c];
    const float v = x[((size_t)n * CCH + c) * LLEN + l0 + tx];
    tile[ty + 8 * i][tx] = (v - mu) * rsg * wc + bc;
  }
  __syncthreads();
#pragma unroll
  for (int i = 0; i < 4; i++) {
    const int l = l0 + ty + 8 * i;
    xn16[((size_t)n * LLEN + l) * CCH + c0 + tx] = f2b(tile[tx][ty + 8 * i]);
  }
}

// ------- QKV GEMM, bf16 MFMA. Block = 64 rows x 64 couts, K=256 fully in LDS.
//         One staging phase (A-tile 32 KB + W-slice 32 KB, coalesced), ONE barrier,
//         then 32 MFMA/wave uninterrupted. grid = (128 rowblk, 4 coutblk, 3 wsel). -------
__global__ __launch_bounds__(256, 2) void qkv_mfma_kernel(
    const unsigned short* __restrict__ xn16,
    const unsigned short* __restrict__ w16,    // [3][256][256]
    const float* __restrict__ bias_ws,         // [3][256]
    unsigned short* __restrict__ q16,
    unsigned short* __restrict__ k16,
    unsigned short* __restrict__ v16) {
  __shared__ __align__(16) unsigned short aS[64][RS];
  __shared__ __align__(16) unsigned short wS[64][RS];
  const int t = threadIdx.x;
  const int lane = t & 63, wv = t >> 6;
  const int col = lane & 15, quad = lane >> 4;
  const int m0 = blockIdx.x * 64;            // flat (n*L + l) row base
  const int co0 = blockIdx.y * 64;
  const int wsel = blockIdx.z;

  // stage: thread t covers row t>>2, ushort cols (t&3)*64..+63 (128 B, coalesced)
  {
    const int r = t >> 2, cu = (t & 3) * 64;
    const unsigned short* srcA = xn16 + (size_t)(m0 + r) * CCH + cu;
    const unsigned short* srcW = w16 + (size_t)wsel * (CCH * CCH) + (size_t)(co0 + r) * CCH + cu;
#pragma unroll
    for (int i = 0; i < 8; i++)
      *(uint4*)&aS[r][cu + i * 8] = *(const uint4*)(srcA + i * 8);
#pragma unroll
    for (int i = 0; i < 8; i++)
      *(uint4*)&wS[r][cu + i * 8] = *(const uint4*)(srcW + i * 8);
  }
  __syncthreads();

  f32x4 acc[4];
#pragma unroll
  for (int i = 0; i < 4; i++) acc[i] = {0.f, 0.f, 0.f, 0.f};

  if (wsel < 2) {
    // q/k: D[row][cout]; wave owns couts co0+wv*16..+15, all 64 rows
#pragma unroll
    for (int kc = 0; kc < 8; kc++) {
      const bf16x8 bw = *(const bf16x8*)&wS[wv * 16 + col][kc * 32 + quad * 8];
#pragma unroll
      for (int mt = 0; mt < 4; mt++) {
        const bf16x8 ax = *(const bf16x8*)&aS[mt * 16 + col][kc * 32 + quad * 8];
        acc[mt] = __builtin_amdgcn_mfma_f32_16x16x32_bf16(ax, bw, acc[mt], 0, 0, 0);
      }
    }
    unsigned short* dst = (wsel == 0) ? q16 : k16;
    const float bias = bias_ws[wsel * CCH + co0 + wv * 16 + col];
#pragma unroll
    for (int mt = 0; mt < 4; mt++)
#pragma unroll
      for (int r = 0; r < 4; r++)
        dst[(size_t)(m0 + mt * 16 + quad * 4 + r) * CCH + co0 + wv * 16 + col] =
            f2b(acc[mt][r] + bias);
  } else {
    // v: D[cout][l] -> [n,c,l]; wave owns couts co0+wv*16..+15 (A = W), rows via B
#pragma unroll
    for (int kc = 0; kc < 8; kc++) {
      const bf16x8 aw = *(const bf16x8*)&wS[wv * 16 + col][kc * 32 + quad * 8];
#pragma unroll
      for (int ct = 0; ct < 4; ct++) {
        const bf16x8 bx = *(const bf16x8*)&aS[ct * 16 + col][kc * 32 + quad * 8];
        acc[ct] = __builtin_amdgcn_mfma_f32_16x16x32_bf16(aw, bx, acc[ct], 0, 0, 0);
      }
    }
    const int n = m0 >> 12, l0 = m0 & 4095;
#pragma unroll
    for (int ct = 0; ct < 4; ct++)
#pragma unroll
      for (int r = 0; r < 4; r++) {
        const int cout = co0 + wv * 16 + quad * 4 + r;
        v16[((size_t)(n * CCH + cout)) * LLEN + l0 + ct * 16 + col] =
            f2b(acc[ct][r] + bias_ws[2 * CCH + cout]);
      }
  }
}

// ------- Flash attention (round-6-measured structure): LDS-staged K/V, 2^s softmax,
//         MFMA denominators, stride-72 b128 frags; HW bf16 pack. -------
__global__ __launch_bounds__(256, 4) void attn_mfma_kernel(
    const unsigned short* __restrict__ q16,   // [n,l,c], pre-scaled (QSCALE folded)
    const unsigned short* __restrict__ k16,   // [n,l,c]
    const unsigned short* __restrict__ v16,   // [n,c,l]
    unsigned short* __restrict__ opA,         // bf16 parts 0,1 (each [n,l,c])
    unsigned short* __restrict__ opB,         // bf16 parts 2,3
    float* __restrict__ lpart) {              // [part][n][h][l]
  __shared__ __align__(16) unsigned short kT[64][72];     // [key][ch]
  __shared__ __align__(16) unsigned short vT[64][72];     // [ch][key]
  __shared__ __align__(16) unsigned short pT[4][32][72];  // per-wave [qrow][key]
  const int t = threadIdx.x;
  const int lane = t & 63, wv = t >> 6;
  const int col = lane & 15, quad = lane >> 4;
  const int q0 = blockIdx.x * QTILE;
  const int n = blockIdx.y >> 2, h = blockIdx.y & 3;
  const int part = blockIdx.z;
  const int hc = h * HD;
  const size_t baseNL = (size_t)n * LLEN;
  const int m_base = q0 + wv * 32;

  bf16x8 bq[2][2];
#pragma unroll
  for (int mt = 0; mt < 2; mt++) {
    const unsigned short* qr = q16 + (baseNL + m_base + mt * 16 + col) * CCH + hc + quad * 8;
    bq[mt][0] = *(const bf16x8*)qr;
    bq[mt][1] = *(const bf16x8*)(qr + 32);
  }
  bf16x8 bones;
#pragma unroll
  for (int i = 0; i < 8; i++) bones[i] = (short)0x3F80;   // bf16 1.0

  f32x4 o[2][4], lacc[2];
#pragma unroll
  for (int mt = 0; mt < 2; mt++) {
    lacc[mt] = {0.f, 0.f, 0.f, 0.f};
#pragma unroll
    for (int ct = 0; ct < 4; ct++) o[mt][ct] = {0.f, 0.f, 0.f, 0.f};
  }

  const int srow = t >> 3;
  const int scol = (t & 7) * 8;
  const unsigned short* kgp = k16 + (baseNL + srow) * CCH + hc + scol;
  const unsigned short* vgp = v16 + ((size_t)(n * CCH + hc + srow)) * LLEN + scol;
  const size_t krstep = (size_t)32 * CCH;
  const size_t vrstep = (size_t)32 * LLEN;

  int kt = part * KEYS_PER_PART;
  uint4 rk0 = *(const uint4*)(kgp + (size_t)kt * CCH);
  uint4 rk1 = *(const uint4*)(kgp + (size_t)kt * CCH + krstep);
  uint4 rv0 = *(const uint4*)(vgp + kt);
  uint4 rv1 = *(const uint4*)(vgp + kt + vrstep);

  for (int it = 0; it < AITERS; it++) {
    __syncthreads();
    *(uint4*)&kT[srow][scol]      = rk0;
    *(uint4*)&kT[srow + 32][scol] = rk1;
    *(uint4*)&vT[srow][scol]      = rv0;
    *(uint4*)&vT[srow + 32][scol] = rv1;
    const int ktn = (it + 1 < AITERS) ? kt + KTILE : kt;
    rk0 = *(const uint4*)(kgp + (size_t)ktn * CCH);
    rk1 = *(const uint4*)(kgp + (size_t)ktn * CCH + krstep);
    rv0 = *(const uint4*)(vgp + ktn);
    rv1 = *(const uint4*)(vgp + ktn + vrstep);
    __syncthreads();

#pragma unroll
    for (int nt = 0; nt < 4; nt++) {
      const bf16x8 a0 = *(const bf16x8*)&kT[nt * 16 + col][quad * 8];
      const bf16x8 a1 = *(const bf16x8*)&kT[nt * 16 + col][32 + quad * 8];
#pragma unroll
      for (int mt = 0; mt < 2; mt++) {
        f32x4 s = {0.f, 0.f, 0.f, 0.f};
        s = __builtin_amdgcn_mfma_f32_16x16x32_bf16(a0, bq[mt][0], s, 0, 0, 0);
        s = __builtin_amdgcn_mfma_f32_16x16x32_bf16(a1, bq[mt][1], s, 0, 0, 0);
        const float p0 = exp2_(s[0]);
        const float p1 = exp2_(s[1]);
        const float p2 = exp2_(s[2]);
        const float p3 = exp2_(s[3]);
        uint2 w;
        w.x = pack2bf(p0, p1);
        w.y = pack2bf(p2, p3);
        *(uint2*)&pT[wv][mt * 16 + col][nt * 16 + quad * 4] = w;
      }
    }
    bf16x8 pa[2][2];
#pragma unroll
    for (int mt = 0; mt < 2; mt++) {
      pa[mt][0] = *(const bf16x8*)&pT[wv][mt * 16 + col][quad * 8];
      pa[mt][1] = *(const bf16x8*)&pT[wv][mt * 16 + col][32 + quad * 8];
      lacc[mt] = __builtin_amdgcn_mfma_f32_16x16x32_bf16(pa[mt][0], bones, lacc[mt], 0, 0, 0);
      lacc[mt] = __builtin_amdgcn_mfma_f32_16x16x32_bf16(pa[mt][1], bones, lacc[mt], 0, 0, 0);
    }
#pragma unroll
    for (int ct = 0; ct < 4; ct++) {
      const bf16x8 b0 = *(const bf16x8*)&vT[ct * 16 + col][quad * 8];
      const bf16x8 b1 = *(const bf16x8*)&vT[ct * 16 + col][32 + quad * 8];
#pragma unroll
      for (int mt = 0; mt < 2; mt++) {
        o[mt][ct] = __builtin_amdgcn_mfma_f32_16x16x32_bf16(pa[mt][0], b0, o[mt][ct], 0, 0, 0);
        o[mt][ct] = __builtin_amdgcn_mfma_f32_16x16x32_bf16(pa[mt][1], b1, o[mt][ct], 0, 0, 0);
      }
    }
    kt = ktn;
  }

  if (col == 0) {
#pragma unroll
    for (int mt = 0; mt < 2; mt++)
#pragma unroll
      for (int r = 0; r < 4; r++)
        lpart[((size_t)(part * NBATCH + n) * NHEAD + h) * LLEN +
              m_base + mt * 16 + quad * 4 + r] = lacc[mt][r];
  }
  const size_t TS = (size_t)NBATCH * LLEN * CCH;
  unsigned short* op = (part < 2) ? (opA + (size_t)part * TS) : (opB + (size_t)(part - 2) * TS);
#pragma unroll
  for (int mt = 0; mt < 2; mt++)
#pragma unroll
    for (int r = 0; r < 4; r++) {
      const size_t rowoff = (baseNL + m_base + mt * 16 + quad * 4 + r) * CCH + hc;
#pragma unroll
      for (int ct = 0; ct < 4; ct++)
        op[rowoff + ct * 16 + col] = f2b(o[mt][ct][r]);
    }
}

// ------- Proj GEMM: block = 64 rows x 64 couts, K=256 in LDS. A-staging fuses
//         split-K combine + 1/l normalize (head = chunk index). One barrier. -------
__global__ __launch_bounds__(256, 2) void proj_mfma_kernel(
    const unsigned short* __restrict__ opA,     // bf16 parts 0,1
    const unsigned short* __restrict__ opB,     // bf16 parts 2,3
    const float* __restrict__ lpart,            // [part][n][h][l]
    const unsigned short* __restrict__ pw16,    // [256][256] bf16
    const float* __restrict__ pbias,            // [256]
    const float* __restrict__ x,
    float* __restrict__ out) {
  __shared__ __align__(16) unsigned short aS[64][RS];
  __shared__ __align__(16) unsigned short wS[64][RS];
  const size_t TS = (size_t)NBATCH * LLEN * CCH;
  const size_t LPS = (size_t)NBATCH * NHEAD * LLEN;
  const int t = threadIdx.x;
  const int lane = t & 63, wv = t >> 6;
  const int col = lane & 15, quad = lane >> 4;
  const int m0 = blockIdx.x * 64;
  const int co0 = blockIdx.y * 64;
  const int n = m0 >> 12, l0 = m0 & 4095;

  {
    const int r = t >> 2, cu = (t & 3) * 64;   // cu/64 = head for this chunk
    // W slice
    const unsigned short* srcW = pw16 + (size_t)(co0 + r) * CCH + cu;
#pragma unroll
    for (int i = 0; i < 8; i++)
      *(uint4*)&wS[r][cu + i * 8] = *(const uint4*)(srcW + i * 8);
    // A = sum of 4 partials * (1/l), head-constant per chunk
    const int l = l0 + r;
    const int h = t & 3;
    float ls = 0.f;
#pragma unroll
    for (int p = 0; p < 4; p++)
      ls += lpart[p * LPS + ((size_t)n * NHEAD + h) * LLEN + l];
    const float linv = 1.0f / ls;
    const size_t e0 = (size_t)(m0 + r) * CCH + cu;
#pragma unroll
    for (int i = 0; i < 8; i++) {
      const size_t e = e0 + (size_t)i * 8;
      const uint4 u0 = *(const uint4*)(opA + e);
      const uint4 u1 = *(const uint4*)(opA + TS + e);
      const uint4 u2 = *(const uint4*)(opB + e);
      const uint4 u3 = *(const uint4*)(opB + TS + e);
      uint4 res;
#pragma unroll
      for (int j = 0; j < 4; j++) {
        const unsigned a = (&u0.x)[j], bb = (&u1.x)[j], cc = (&u2.x)[j], dd = (&u3.x)[j];
        const float lo = (b2f((unsigned short)a) + b2f((unsigned short)bb) +
                          b2f((unsigned short)cc) + b2f((unsigned short)dd)) * linv;
        const float hi = (b2f((unsigned short)(a >> 16)) + b2f((unsigned short)(bb >> 16)) +
                          b2f((unsigned short)(cc >> 16)) + b2f((unsigned short)(dd >> 16))) * linv;
        (&res.x)[j] = pack2bf(lo, hi);
      }
      *(uint4*)&aS[r][cu + i * 8] = res;
    }
  }
  __syncthreads();

  f32x4 acc[4];
#pragma unroll
  for (int i = 0; i < 4; i++) acc[i] = {0.f, 0.f, 0.f, 0.f};
  // D[cout][l]; wave owns couts co0+wv*16..+15 (A = W), rows via B
#pragma unroll
  for (int kc = 0; kc < 8; kc++) {
    const bf16x8 aw = *(const bf16x8*)&wS[wv * 16 + col][kc * 32 + quad * 8];
#pragma unroll
    for (int ct = 0; ct < 4; ct++) {
      const bf16x8 ba = *(const bf16x8*)&aS[ct * 16 + col][kc * 32 + quad * 8];
      acc[ct] = __builtin_amdgcn_mfma_f32_16x16x32_bf16(aw, ba, acc[ct], 0, 0, 0);
    }
  }
#pragma unroll
  for (int ct = 0; ct < 4; ct++)
#pragma unroll
    for (int r = 0; r < 4; r++) {
      const int cout = co0 + wv * 16 + quad * 4 + r;
      const size_t idx = ((size_t)(n * CCH + cout)) * LLEN + l0 + ct * 16 + col;
      out[idx] = acc[ct][r] + pbias[cout] + x[idx];
    }
}

extern "C" void kernel_launch(void* const* d_in, const int* in_sizes, int n_in,
                              void* d_out, int out_size, void* d_ws, size_t ws_size,
                              hipStream_t stream) {
  (void)in_sizes; (void)n_in; (void)out_size; (void)ws_size;
  const float* x      = (const float*)d_in[0];
  const int*   mask   = (const int*)d_in[1];
  const float* norm_w = (const float*)d_in[2];
  const float* norm_b = (const float*)d_in[3];
  const float* q_w    = (const float*)d_in[4];
  const float* q_b    = (const float*)d_in[5];
  const float* k_w    = (const float*)d_in[6];
  const float* k_b    = (const float*)d_in[7];
  const float* v_w    = (const float*)d_in[8];
  const float* v_b    = (const float*)d_in[9];
  const float* p_w    = (const float*)d_in[10];
  const float* p_b    = (const float*)d_in[11];

  const size_t TSZ = (size_t)NBATCH * LLEN * CCH;   // 2097152 elements
  unsigned short* xn16 = (unsigned short*)d_ws;     // TSZ
  unsigned short* q16  = xn16 + TSZ;
  unsigned short* k16  = q16 + TSZ;
  unsigned short* v16  = k16 + TSZ;
  unsigned short* opA  = v16 + TSZ;                 // 2*TSZ
  unsigned short* opB  = opA + 2 * TSZ;             // 2*TSZ
  unsigned short* w16  = opB + 2 * TSZ;             // 4*65536
  float* bias_ws = (float*)(w16 + 4 * 65536);       // 4*256
  float* lpart   = bias_ws + 1024;                  // KSPLIT*N*H*L
  float* part    = lpart + (size_t)KSPLIT * NBATCH * NHEAD * LLEN;  // 256
  // total ~33 MB

  float* out  = (float*)d_out;
  float* out2 = out + TSZ;   // mask chunk

  setup_kernel<<<416, 256, 0, stream>>>(q_w, k_w, v_w, p_w, q_b, k_b, v_b, p_b,
                                        x, mask, w16, bias_ws, part, out2);
  gn_apply_kernel<<<dim3(LLEN / 32, CCH / 32, NBATCH), 256, 0, stream>>>(
      x, norm_w, norm_b, part, xn16);
  qkv_mfma_kernel<<<dim3((NBATCH * LLEN) / 64, CCH / 64, 3), 256, 0, stream>>>(
      xn16, w16, bias_ws, q16, k16, v16);
  attn_mfma_kernel<<<dim3(LLEN / QTILE, NBATCH * NHEAD, KSPLIT), 256, 0, stream>>>(
      q16, k16, v16, opA, opB, lpart);
  proj_mfma_kernel<<<dim3((NBATCH * LLEN) / 64, CCH / 64), 256, 0, stream>>>(
      opA, opB, lpart, w16 + 3 * 65536, bias_ws + 768, x, out);
}